// Round 1
// baseline (298.269 us; speedup 1.0000x reference)
//
#include <hip/hip_runtime.h>

// All inputs and the output are float32 (established rounds 0-3).
// R8: mega was latency-bound (VALUBusy 28%, Occ 15%, HBM 3%): 192 blocks x 8 waves
// = 2 waves/SIMD on 192/256 CUs, each thread chaining ~1500 L2-latency loads.
// This round: (a) hoist the 24x-redundant shared-layer matvec (sh = hid@st_w2)
// into a tiny l2_kernel; (b) mega goes to 1024-thread blocks (4 waves/SIMD) with
// split-K-by-4 partials in LDS, halving-to-quartering every serial load chain.

__device__ __forceinline__ float leaky(float v) { return v >= 0.f ? v : 0.2f * v; }

// ---------- D0: L1 split-K6 (slice 128): hid1p[z] = (z==0? st_b1:0) + h @ st_w1[slice z]
__global__ __launch_bounds__(256, 2) void l1_kernel(
    const float* __restrict__ h, const float* __restrict__ W,
    const float* __restrict__ bias, float* __restrict__ outp)
{
    __shared__ __align__(16) float a_lds[128][34];
    __shared__ __align__(16) float w_lds[128][34];
    const int tid = threadIdx.x;
    const int x = blockIdx.x, z = blockIdx.z;
    const int b0 = (x & 1) * 32, n0 = (x >> 1) * 32;
    const int nq = tid & 15, bq = tid >> 4;
    const int k0 = z * 128;
    float a00, a01, a10, a11;
    if (z == 0) {
        float bv0 = bias[n0 + nq * 2], bv1 = bias[n0 + nq * 2 + 1];
        a00 = bv0; a01 = bv1; a10 = bv0; a11 = bv1;
    } else { a00 = a01 = a10 = a11 = 0.f; }
    #pragma unroll
    for (int j = 0; j < 16; ++j) {
        int idx = tid + j * 256;
        int k = idx & 127, c = idx >> 7;
        a_lds[k][c] = h[(size_t)(b0 + c) * 768 + k0 + k];
        int n = idx & 31, kk = idx >> 5;
        w_lds[kk][n] = W[(size_t)(k0 + kk) * 512 + n0 + n];
    }
    __syncthreads();
    #pragma unroll 32
    for (int kk = 0; kk < 128; ++kk) {
        float2 a = *(const float2*)&a_lds[kk][bq * 2];
        float2 w = *(const float2*)&w_lds[kk][nq * 2];
        a00 += a.x * w.x; a01 += a.x * w.y;
        a10 += a.y * w.x; a11 += a.y * w.y;
    }
    float* ob = outp + (size_t)z * 32768;
    ob[(size_t)(b0 + bq * 2) * 512 + n0 + nq * 2]         = a00;
    ob[(size_t)(b0 + bq * 2) * 512 + n0 + nq * 2 + 1]     = a01;
    ob[(size_t)(b0 + bq * 2 + 1) * 512 + n0 + nq * 2]     = a10;
    ob[(size_t)(b0 + bq * 2 + 1) * 512 + n0 + nq * 2 + 1] = a11;
}

// ---------- D0b: shared layer 2, computed ONCE (was recomputed by all 24 rank-blocks).
// sh[64][256] = (leaky(sum6 hid1p)) @ st_w2 + st_b2.  16 blocks x 1024 thr,
// 4 rows/block, K=512 split across 4 sub-groups of 128.
__global__ __launch_bounds__(1024, 4) void l2_kernel(
    const float* __restrict__ hid1p, const float* __restrict__ st_w2,
    const float* __restrict__ st_b2, float* __restrict__ sh)
{
    __shared__ __align__(16) float hid_s[4][512];
    __shared__ __align__(16) float ps2[4][4][256];
    const int tid = threadIdx.x;
    const int b0 = blockIdx.x * 4;
    if (tid < 512) {
        int row = tid >> 7, j4 = tid & 127;
        const float4* hp = (const float4*)hid1p;
        size_t off = (size_t)(b0 + row) * 128 + j4;
        float4 v0 = hp[off],         v1 = hp[8192 + off],  v2 = hp[16384 + off];
        float4 v3 = hp[24576 + off], v4 = hp[32768 + off], v5 = hp[40960 + off];
        float4 s;
        s.x = leaky(v0.x + v1.x + v2.x + v3.x + v4.x + v5.x);
        s.y = leaky(v0.y + v1.y + v2.y + v3.y + v4.y + v5.y);
        s.z = leaky(v0.z + v1.z + v2.z + v3.z + v4.z + v5.z);
        s.w = leaky(v0.w + v1.w + v2.w + v3.w + v4.w + v5.w);
        ((float4*)&hid_s[row][0])[j4] = s;
    }
    __syncthreads();
    {
        const int col = tid & 255, kg = tid >> 8;
        float a0 = 0.f, a1 = 0.f, a2 = 0.f, a3 = 0.f;
        const float* wp = st_w2 + (size_t)(kg * 128) * 256 + col;
        const int o = kg * 128;
        #pragma unroll 4
        for (int d = 0; d < 128; d += 4) {
            float w0 = wp[(size_t)(d + 0) * 256], w1 = wp[(size_t)(d + 1) * 256];
            float w2 = wp[(size_t)(d + 2) * 256], w3 = wp[(size_t)(d + 3) * 256];
            float4 s0 = *(const float4*)&hid_s[0][o + d];
            float4 s1 = *(const float4*)&hid_s[1][o + d];
            float4 s2 = *(const float4*)&hid_s[2][o + d];
            float4 s3 = *(const float4*)&hid_s[3][o + d];
            a0 += s0.x * w0 + s0.y * w1 + s0.z * w2 + s0.w * w3;
            a1 += s1.x * w0 + s1.y * w1 + s1.z * w2 + s1.w * w3;
            a2 += s2.x * w0 + s2.y * w1 + s2.z * w2 + s2.w * w3;
            a3 += s3.x * w0 + s3.y * w1 + s3.z * w2 + s3.w * w3;
        }
        ps2[kg][0][col] = a0; ps2[kg][1][col] = a1;
        ps2[kg][2][col] = a2; ps2[kg][3][col] = a3;
    }
    __syncthreads();
    {
        int row = tid >> 8, c = tid & 255;
        sh[(size_t)(b0 + row) * 256 + c] = st_b2[c]
            + ps2[0][row][c] + ps2[1][row][c] + ps2[2][row][c] + ps2[3][row][c];
    }
}

// ---------- D1: mega-middle. 192 blocks x 1024 thr. blk -> (r = blk%24, bt = blk/24),
// 8 rows/block. col = tid&255, sub = tid>>8 (0..3) splits K (or heads in G2/G3).
// All reductions: partial-per-sub into LDS ps[], barrier, combine.
__global__ __launch_bounds__(1024, 4) void mega_kernel(
    const float* __restrict__ sh,
    const float* __restrict__ rank_emb,
    const float* __restrict__ rm_w1, const float* __restrict__ rm_b1,
    const float* __restrict__ rm_w2, const float* __restrict__ rm_b2,
    const float* __restrict__ mx_w1, const float* __restrict__ mx_b1,
    const float* __restrict__ mx_w2, const float* __restrict__ mx_b2,
    const float* __restrict__ my_w1, const float* __restrict__ my_b1,
    const float* __restrict__ my_w2, const float* __restrict__ my_b2,
    const float* __restrict__ ax_w1, const float* __restrict__ ax_b1,
    const float* __restrict__ ax_w2, const float* __restrict__ ax_b2,
    const float* __restrict__ ay_w1, const float* __restrict__ ay_b1,
    const float* __restrict__ ay_w2, const float* __restrict__ ay_b2,
    float* __restrict__ Pcat)
{
    __shared__ __align__(16) float sh_s[8][256];     // 8 KB
    __shared__ __align__(16) float hdn_s[8][256];    // 8 KB
    __shared__ __align__(16) float rf_s[8][256];     // 8 KB
    __shared__ __align__(16) float hc_s[2][8][256];  // 16 KB
    __shared__ __align__(16) float ps[4][8][256];    // 32 KB scratch (reused per phase)
    __shared__ __align__(16) float pre_ps[4][256];   // 4 KB
    __shared__ __align__(16) float remb_s[256];      // 1 KB   (total ~77 KB)
    const int tid = threadIdx.x;
    const int blk = blockIdx.x;
    const int r = blk % 24;          // blk = r (mod 8): all 8 blocks of a rank on one XCD
    const int bt = blk / 24;         // 0..7
    const int b0 = bt * 8;
    const int col = tid & 255;
    const int sub = tid >> 8;        // 0..3

    // stage: sh rows + rank_emb row
    if (tid < 512) {
        int row = tid >> 6, j4 = tid & 63;
        ((float4*)&sh_s[row][0])[j4] = ((const float4*)sh)[(size_t)(b0 + row) * 64 + j4];
    } else if (tid < 576) {
        int j4 = tid - 512;
        ((float4*)remb_s)[j4] = ((const float4*)rank_emb)[(size_t)r * 64 + j4];
    }
    __syncthreads();

    // merged prebias + L3 partials (both depend only on the stage)
    {
        // prebias partial: re[col] part over K-slice [256+sub*64, 256+sub*64+64)
        float accp = 0.f;
        const float* wb = rm_w1 + ((size_t)r * 512 + 256 + sub * 64) * 256 + col;
        #pragma unroll 8
        for (int d = 0; d < 64; d += 4) {
            float w0 = wb[(size_t)(d + 0) * 256], w1 = wb[(size_t)(d + 1) * 256];
            float w2 = wb[(size_t)(d + 2) * 256], w3 = wb[(size_t)(d + 3) * 256];
            float4 e = *(const float4*)&remb_s[sub * 64 + d];
            accp += e.x * w0 + e.y * w1 + e.z * w2 + e.w * w3;
        }
        pre_ps[sub][col] = accp;

        // L3 partial: hdn over K-slice [sub*64, sub*64+64), 8 rows
        float acc[8];
        #pragma unroll
        for (int i = 0; i < 8; ++i) acc[i] = 0.f;
        const float* wp = rm_w1 + ((size_t)r * 512 + sub * 64) * 256 + col;
        const int o = sub * 64;
        #pragma unroll 4
        for (int d = 0; d < 64; d += 4) {
            float w0 = wp[(size_t)(d + 0) * 256], w1 = wp[(size_t)(d + 1) * 256];
            float w2 = wp[(size_t)(d + 2) * 256], w3 = wp[(size_t)(d + 3) * 256];
            #pragma unroll
            for (int i = 0; i < 8; ++i) {
                float4 s = *(const float4*)&sh_s[i][o + d];
                acc[i] += s.x * w0 + s.y * w1 + s.z * w2 + s.w * w3;
            }
        }
        #pragma unroll
        for (int i = 0; i < 8; ++i) ps[sub][i][col] = acc[i];
    }
    __syncthreads();

    // combine hdn = leaky(b1 + prebias + sum_k L3 partials)
    #pragma unroll
    for (int t = 0; t < 2; ++t) {
        int o = tid + t * 1024;
        int i = o >> 8, c = o & 255;
        float v = rm_b1[r * 256 + c]
                + pre_ps[0][c] + pre_ps[1][c] + pre_ps[2][c] + pre_ps[3][c]
                + ps[0][i][c] + ps[1][i][c] + ps[2][i][c] + ps[3][i][c];
        hdn_s[i][c] = leaky(v);
    }
    __syncthreads();

    // L4 partial: rf over K-slice of 64, 8 rows (no activation)
    {
        float acc[8];
        #pragma unroll
        for (int i = 0; i < 8; ++i) acc[i] = 0.f;
        const float* wp = rm_w2 + (size_t)r * 65536 + (size_t)(sub * 64) * 256 + col;
        const int o = sub * 64;
        #pragma unroll 4
        for (int d = 0; d < 64; d += 4) {
            float w0 = wp[(size_t)(d + 0) * 256], w1 = wp[(size_t)(d + 1) * 256];
            float w2 = wp[(size_t)(d + 2) * 256], w3 = wp[(size_t)(d + 3) * 256];
            #pragma unroll
            for (int i = 0; i < 8; ++i) {
                float4 s = *(const float4*)&hdn_s[i][o + d];
                acc[i] += s.x * w0 + s.y * w1 + s.z * w2 + s.w * w3;
            }
        }
        #pragma unroll
        for (int i = 0; i < 8; ++i) ps[sub][i][col] = acc[i];
    }
    __syncthreads();

    #pragma unroll
    for (int t = 0; t < 2; ++t) {
        int o = tid + t * 1024;
        int i = o >> 8, c = o & 255;
        rf_s[i][c] = rm_b2[r * 256 + c]
                   + ps[0][i][c] + ps[1][i][c] + ps[2][i][c] + ps[3][i][c];
    }
    __syncthreads();

    // head pointers: r<16 -> mx(y=r)/my(y=16+r); r>=16 -> ax(y=32+rw)/ay(y=40+rw)
    const float *W1_0, *B1_0, *W2_0, *B2_0, *W1_1, *B1_1, *W2_1, *B2_1;
    int y0, y1;
    if (r < 16) {
        y0 = r;       W1_0 = mx_w1 + (size_t)r * 65536;  B1_0 = mx_b1 + r * 256;
                      W2_0 = mx_w2 + (size_t)r * 6144;   B2_0 = mx_b2 + r * 24;
        y1 = 16 + r;  W1_1 = my_w1 + (size_t)r * 65536;  B1_1 = my_b1 + r * 256;
                      W2_1 = my_w2 + (size_t)r * 6144;   B2_1 = my_b2 + r * 24;
    } else {
        int rw = r - 16;
        y0 = 32 + rw; W1_0 = ax_w1 + (size_t)rw * 65536; B1_0 = ax_b1 + rw * 256;
                      W2_0 = ax_w2 + (size_t)rw * 6144;  B2_0 = ax_b2 + rw * 24;
        y1 = 40 + rw; W1_1 = ay_w1 + (size_t)rw * 65536; B1_1 = ay_b1 + rw * 256;
                      W2_1 = ay_w2 + (size_t)rw * 6144;  B2_1 = ay_b2 + rw * 24;
    }

    // G2 partial: sub = (kg<<1)|h -> head h, K-slice of 128
    {
        const int h = sub & 1, kg = sub >> 1;
        const float* wp = (h ? W1_1 : W1_0) + (size_t)(kg * 128) * 256 + col;
        const int o = kg * 128;
        float acc[8];
        #pragma unroll
        for (int i = 0; i < 8; ++i) acc[i] = 0.f;
        #pragma unroll 4
        for (int d = 0; d < 128; d += 4) {
            float w0 = wp[(size_t)(d + 0) * 256], w1 = wp[(size_t)(d + 1) * 256];
            float w2 = wp[(size_t)(d + 2) * 256], w3 = wp[(size_t)(d + 3) * 256];
            #pragma unroll
            for (int i = 0; i < 8; ++i) {
                float4 s = *(const float4*)&rf_s[i][o + d];
                acc[i] += s.x * w0 + s.y * w1 + s.z * w2 + s.w * w3;
            }
        }
        #pragma unroll
        for (int i = 0; i < 8; ++i) ps[sub][i][col] = acc[i];
    }
    __syncthreads();

    // combine hc[h] = leaky(B1 + kg0 + kg1); thread covers (h=sub&1, 4 rows)
    {
        const int h = sub & 1, i0 = (sub >> 1) * 4;
        float bv = (h ? B1_1 : B1_0)[col];
        #pragma unroll
        for (int q = 0; q < 4; ++q) {
            int i = i0 + q;
            hc_s[h][i][col] = leaky(bv + ps[h][i][col] + ps[2 + h][i][col]);
        }
    }
    __syncthreads();

    // G3 partial: 2 heads x 8 rows x 24 cols x 2 K-halves = 768 threads
    float* psf = &ps[0][0][0];
    if (tid < 768) {
        int h = tid >= 384 ? 1 : 0;
        int q = tid - h * 384;
        int kg = q & 1;
        int c2 = q >> 1;                 // 0..191
        int row = c2 / 24, cj = c2 - row * 24;
        const float* wp = (h ? W2_1 : W2_0) + (size_t)(kg * 128) * 24 + cj;
        const float* hp = &hc_s[h][row][kg * 128];
        float acc = 0.f;
        #pragma unroll 8
        for (int d = 0; d < 128; d += 4) {
            float w0 = wp[(d + 0) * 24], w1 = wp[(d + 1) * 24];
            float w2 = wp[(d + 2) * 24], w3 = wp[(d + 3) * 24];
            float4 s = *(const float4*)&hp[d];
            acc += s.x * w0 + s.y * w1 + s.z * w2 + s.w * w3;
        }
        psf[tid] = acc;
    }
    __syncthreads();

    if (tid < 384) {
        int h = tid >= 192 ? 1 : 0;
        int c2 = tid - h * 192;
        int row = c2 / 24, cj = c2 - row * 24;
        float v = (h ? B2_1 : B2_0)[cj] + psf[h * 384 + c2 * 2] + psf[h * 384 + c2 * 2 + 1];
        int y = h ? y1 : y0;
        Pcat[(size_t)(b0 + row) * 1152 + y * 24 + cj] = v;
    }
}

// ---------- D2: fused spline + depth (unchanged).
// Pcat rows: [Px_m 0..15, Py_m 16..31, Px_a 32..39, Py_a 40..47]
__global__ __launch_bounds__(256, 2) void depth_fused_kernel(
    const float* __restrict__ Pcat,
    const float* __restrict__ mult_w, const float* __restrict__ addx_w,
    const float* __restrict__ addy_w, const float* __restrict__ gbias,
    float* __restrict__ out)
{
    __shared__ float cp[48][25];
    __shared__ float sw[33];
    __shared__ __align__(16) float u_s[16][132];
    __shared__ __align__(16) float v_s[16][132];
    __shared__ float dx_s[128], dy_s[128];
    const int tid = threadIdx.x;
    const int b = blockIdx.z, h0 = blockIdx.y * 128, w0 = blockIdx.x * 128;
    for (int idx = tid; idx < 1152; idx += 256)
        cp[idx / 24][idx % 24] = Pcat[(size_t)b * 1152 + idx];
    if (tid == 0) {
        float e[16], m, s;
        m = -1e30f; for (int i = 0; i < 16; ++i) m = fmaxf(m, mult_w[i]);
        s = 0.f;    for (int i = 0; i < 16; ++i) { e[i] = __expf(mult_w[i] - m); s += e[i]; }
        for (int i = 0; i < 16; ++i) sw[i] = e[i] / s;
        m = -1e30f; for (int i = 0; i < 8; ++i) m = fmaxf(m, addx_w[i]);
        s = 0.f;    for (int i = 0; i < 8; ++i) { e[i] = __expf(addx_w[i] - m); s += e[i]; }
        for (int i = 0; i < 8; ++i) sw[16 + i] = e[i] / s;
        m = -1e30f; for (int i = 0; i < 8; ++i) m = fmaxf(m, addy_w[i]);
        s = 0.f;    for (int i = 0; i < 8; ++i) { e[i] = __expf(addy_w[i] - m); s += e[i]; }
        for (int i = 0; i < 8; ++i) sw[24 + i] = e[i] / s;
        sw[32] = gbias[0];
    }
    __syncthreads();
    {
        const int local = tid & 127;
        const int gpos = (tid < 128 ? w0 : h0) + local;
        const float eps = 0.001f;
        float t = eps + (float)gpos * ((1.f - 2.f * eps) / 511.f);
        float ts = t * 23.f;
        int seg = (int)ts; if (seg > 22) seg = 22;
        float tau = ts - (float)seg;
        tau = fminf(fmaxf(tau, 0.f), 0.9999f);
        float t2 = tau * tau, t3 = t2 * tau;
        float h00 = 2.f * t3 - 3.f * t2 + 1.f;
        float h10 = t3 - 2.f * t2 + tau;
        float h01 = -2.f * t3 + 3.f * t2;
        float h11 = t3 - t2;
        int sm1 = seg > 0 ? seg - 1 : 0;
        int s1 = seg + 1;
        int sp2 = s1 < 23 ? s1 + 1 : 23;
        const float msc = 0.5f / 23.f;
        auto spl = [&](int row) -> float {
            float pk = cp[row][seg], pk1 = cp[row][s1];
            float mk  = msc * (pk1 - cp[row][sm1]);
            float mk1 = msc * (cp[row][sp2] - pk);
            return h00 * pk + h10 * mk + h01 * pk1 + h11 * mk1;
        };
        if (tid < 128) {
            #pragma unroll
            for (int r = 0; r < 16; ++r) u_s[r][local] = sw[r] * spl(r);
            float dx = sw[32];
            #pragma unroll
            for (int r = 0; r < 8; ++r) dx += sw[16 + r] * spl(32 + r);
            dx_s[local] = dx;
        } else {
            #pragma unroll
            for (int r = 0; r < 16; ++r) v_s[r][local] = spl(16 + r);
            float dy = 0.f;
            #pragma unroll
            for (int r = 0; r < 8; ++r) dy += sw[24 + r] * spl(40 + r);
            dy_s[local] = dy;
        }
    }
    __syncthreads();
    const int tw = tid & 15, th = tid >> 4;
    float acc[8][8];
    #pragma unroll
    for (int i = 0; i < 8; ++i)
        #pragma unroll
        for (int j = 0; j < 8; ++j) acc[i][j] = 0.f;
    #pragma unroll
    for (int r = 0; r < 16; ++r) {
        float4 va0 = *(const float4*)&v_s[r][th * 8];
        float4 va1 = *(const float4*)&v_s[r][th * 8 + 4];
        float4 ub0 = *(const float4*)&u_s[r][tw * 8];
        float4 ub1 = *(const float4*)&u_s[r][tw * 8 + 4];
        float va[8] = {va0.x, va0.y, va0.z, va0.w, va1.x, va1.y, va1.z, va1.w};
        float ub[8] = {ub0.x, ub0.y, ub0.z, ub0.w, ub1.x, ub1.y, ub1.z, ub1.w};
        #pragma unroll
        for (int i = 0; i < 8; ++i)
            #pragma unroll
            for (int j = 0; j < 8; ++j)
                acc[i][j] += va[i] * ub[j];
    }
    #pragma unroll
    for (int i = 0; i < 8; ++i) {
        float dyh = dy_s[th * 8 + i];
        float* op = out + (size_t)b * 262144 + (size_t)(h0 + th * 8 + i) * 512 + w0 + tw * 8;
        float4 o0, o1;
        o0.x = acc[i][0] + dx_s[tw * 8 + 0] + dyh;
        o0.y = acc[i][1] + dx_s[tw * 8 + 1] + dyh;
        o0.z = acc[i][2] + dx_s[tw * 8 + 2] + dyh;
        o0.w = acc[i][3] + dx_s[tw * 8 + 3] + dyh;
        o1.x = acc[i][4] + dx_s[tw * 8 + 4] + dyh;
        o1.y = acc[i][5] + dx_s[tw * 8 + 5] + dyh;
        o1.z = acc[i][6] + dx_s[tw * 8 + 6] + dyh;
        o1.w = acc[i][7] + dx_s[tw * 8 + 7] + dyh;
        *(float4*)op = o0;
        *(float4*)(op + 4) = o1;
    }
}

// ---------- host ----------
extern "C" void kernel_launch(void* const* d_in, const int* in_sizes, int n_in,
                              void* d_out, int out_size, void* d_ws, size_t ws_size,
                              hipStream_t stream) {
    const float* in_h     = (const float*)d_in[0];
    const float* rank_emb = (const float*)d_in[1];
    const float* st_w1    = (const float*)d_in[2];
    const float* st_b1    = (const float*)d_in[3];
    const float* st_w2    = (const float*)d_in[4];
    const float* st_b2    = (const float*)d_in[5];
    const float* rm_w1    = (const float*)d_in[6];
    const float* rm_b1    = (const float*)d_in[7];
    const float* rm_w2    = (const float*)d_in[8];
    const float* rm_b2    = (const float*)d_in[9];
    const float* mx_w1    = (const float*)d_in[10];
    const float* mx_b1    = (const float*)d_in[11];
    const float* mx_w2    = (const float*)d_in[12];
    const float* mx_b2    = (const float*)d_in[13];
    const float* my_w1    = (const float*)d_in[14];
    const float* my_b1    = (const float*)d_in[15];
    const float* my_w2    = (const float*)d_in[16];
    const float* my_b2    = (const float*)d_in[17];
    const float* ax_w1    = (const float*)d_in[18];
    const float* ax_b1    = (const float*)d_in[19];
    const float* ax_w2    = (const float*)d_in[20];
    const float* ax_b2    = (const float*)d_in[21];
    const float* ay_w1    = (const float*)d_in[22];
    const float* ay_b1    = (const float*)d_in[23];
    const float* ay_w2    = (const float*)d_in[24];
    const float* ay_b2    = (const float*)d_in[25];
    const float* mult_w   = (const float*)d_in[26];
    const float* addx_w   = (const float*)d_in[27];
    const float* addy_w   = (const float*)d_in[28];
    const float* gbias    = (const float*)d_in[29];
    (void)in_sizes; (void)n_in; (void)out_size; (void)ws_size;

    float* ws = (float*)d_ws;
    float* hid1p = ws;               // 6 x (64x512) = 196608 floats
    float* Pcat  = ws + 196608;      // 64x48x24     = 73728 floats
    float* shbuf = ws + 270336;      // 64x256       = 16384 floats

    // D0: L1 split-K6 -> hid1p[6]
    l1_kernel<<<dim3(32, 1, 6), 256, 0, stream>>>(in_h, st_w1, st_b1, hid1p);

    // D0b: shared layer 2 (once, not per-rank)
    l2_kernel<<<16, 1024, 0, stream>>>(hid1p, st_w2, st_b2, shbuf);

    // D1: mega-middle -> Pcat (1D grid, XCD-clustered by rank)
    mega_kernel<<<192, 1024, 0, stream>>>(
        shbuf, rank_emb,
        rm_w1, rm_b1, rm_w2, rm_b2,
        mx_w1, mx_b1, mx_w2, mx_b2,
        my_w1, my_b1, my_w2, my_b2,
        ax_w1, ax_b1, ax_w2, ax_b2,
        ay_w1, ay_b1, ay_w2, ay_b2,
        Pcat);

    // D2: fused spline + depth
    depth_fused_kernel<<<dim3(4, 4, 64), 256, 0, stream>>>(
        Pcat, mult_w, addx_w, addy_w, gbias, (float*)d_out);
}

// Round 3
// 240.128 us; speedup vs baseline: 1.2421x; 1.2421x over previous
//
#include <hip/hip_runtime.h>

// All inputs and the output are float32 (established rounds 0-3).
// R10 = R9 resubmitted verbatim: R9's bench died to an infra flake ("container
// failed twice"), no kernel signal. Audit found no hang/trap risk (uniform
// barriers, 23KB LDS, 1.12MB ws, no forbidden host APIs).
// R9 rationale: R8's 1024-thr split-K mega spilled to scratch (WRITE_SIZE
// 288KB -> 144MB; VALUBusy 14%) and regressed 83->130us. Keep the l2-hoist,
// revert mega to R7's proven 512-thread no-spill phase structure, and get
// parallelism by halving rows/block: 4 rows x 384 blocks -> all 256 CUs busy,
// ~2 blocks/CU (LDS 23KB, launch_bounds(512,4)). XCD clustering preserved:
// blk%8 == r%8 for all 16 blocks of rank r.

__device__ __forceinline__ float leaky(float v) { return v >= 0.f ? v : 0.2f * v; }

// ---------- D0: L1 split-K6 (slice 128): hid1p[z] = (z==0? st_b1:0) + h @ st_w1[slice z]
__global__ __launch_bounds__(256, 2) void l1_kernel(
    const float* __restrict__ h, const float* __restrict__ W,
    const float* __restrict__ bias, float* __restrict__ outp)
{
    __shared__ __align__(16) float a_lds[128][34];
    __shared__ __align__(16) float w_lds[128][34];
    const int tid = threadIdx.x;
    const int x = blockIdx.x, z = blockIdx.z;
    const int b0 = (x & 1) * 32, n0 = (x >> 1) * 32;
    const int nq = tid & 15, bq = tid >> 4;
    const int k0 = z * 128;
    float a00, a01, a10, a11;
    if (z == 0) {
        float bv0 = bias[n0 + nq * 2], bv1 = bias[n0 + nq * 2 + 1];
        a00 = bv0; a01 = bv1; a10 = bv0; a11 = bv1;
    } else { a00 = a01 = a10 = a11 = 0.f; }
    #pragma unroll
    for (int j = 0; j < 16; ++j) {
        int idx = tid + j * 256;
        int k = idx & 127, c = idx >> 7;
        a_lds[k][c] = h[(size_t)(b0 + c) * 768 + k0 + k];
        int n = idx & 31, kk = idx >> 5;
        w_lds[kk][n] = W[(size_t)(k0 + kk) * 512 + n0 + n];
    }
    __syncthreads();
    #pragma unroll 32
    for (int kk = 0; kk < 128; ++kk) {
        float2 a = *(const float2*)&a_lds[kk][bq * 2];
        float2 w = *(const float2*)&w_lds[kk][nq * 2];
        a00 += a.x * w.x; a01 += a.x * w.y;
        a10 += a.y * w.x; a11 += a.y * w.y;
    }
    float* ob = outp + (size_t)z * 32768;
    ob[(size_t)(b0 + bq * 2) * 512 + n0 + nq * 2]         = a00;
    ob[(size_t)(b0 + bq * 2) * 512 + n0 + nq * 2 + 1]     = a01;
    ob[(size_t)(b0 + bq * 2 + 1) * 512 + n0 + nq * 2]     = a10;
    ob[(size_t)(b0 + bq * 2 + 1) * 512 + n0 + nq * 2 + 1] = a11;
}

// ---------- D0b: shared layer 2, computed ONCE. 32 blocks x 512 thr, 2 rows/block,
// K=512 split across the two 256-thread halves (kg = tid>>8).
__global__ __launch_bounds__(512, 2) void l2_kernel(
    const float* __restrict__ hid1p, const float* __restrict__ st_w2,
    const float* __restrict__ st_b2, float* __restrict__ sh)
{
    __shared__ __align__(16) float hid_s[2][512];
    __shared__ __align__(16) float ps2[2][2][256];
    const int tid = threadIdx.x;
    const int b0 = blockIdx.x * 2;
    if (tid < 256) {
        int row = tid >> 7, j4 = tid & 127;
        const float4* hp = (const float4*)hid1p;
        size_t off = (size_t)(b0 + row) * 128 + j4;
        float4 v0 = hp[off],         v1 = hp[8192 + off],  v2 = hp[16384 + off];
        float4 v3 = hp[24576 + off], v4 = hp[32768 + off], v5 = hp[40960 + off];
        float4 s;
        s.x = leaky(v0.x + v1.x + v2.x + v3.x + v4.x + v5.x);
        s.y = leaky(v0.y + v1.y + v2.y + v3.y + v4.y + v5.y);
        s.z = leaky(v0.z + v1.z + v2.z + v3.z + v4.z + v5.z);
        s.w = leaky(v0.w + v1.w + v2.w + v3.w + v4.w + v5.w);
        ((float4*)&hid_s[row][0])[j4] = s;
    }
    __syncthreads();
    {
        const int col = tid & 255, kg = tid >> 8;
        const int o = kg * 256;
        float a0 = 0.f, a1 = 0.f;
        const float* wp = st_w2 + (size_t)o * 256 + col;
        #pragma unroll 4
        for (int d = 0; d < 256; d += 4) {
            float w0 = wp[(size_t)(d + 0) * 256], w1 = wp[(size_t)(d + 1) * 256];
            float w2 = wp[(size_t)(d + 2) * 256], w3 = wp[(size_t)(d + 3) * 256];
            float4 s0 = *(const float4*)&hid_s[0][o + d];
            float4 s1 = *(const float4*)&hid_s[1][o + d];
            a0 += s0.x * w0 + s0.y * w1 + s0.z * w2 + s0.w * w3;
            a1 += s1.x * w0 + s1.y * w1 + s1.z * w2 + s1.w * w3;
        }
        ps2[kg][0][col] = a0; ps2[kg][1][col] = a1;
    }
    __syncthreads();
    {
        int row = tid >> 8, c = tid & 255;
        sh[(size_t)(b0 + row) * 256 + c] = st_b2[c] + ps2[0][row][c] + ps2[1][row][c];
    }
}

// ---------- D1: mega-middle. 384 blocks x 512 thr. blk -> (r = blk%24, bt = blk/24),
// 4 batch rows per block; col = tid&255, rh = tid>>8. L3/L4: half rh handles rows
// rh*2..rh*2+1. G2/G3: half rh handles head rh (all 4 rows). All weight loads
// coalesced (stride-256 column reads); activations in LDS. R7 codegen pattern.
__global__ __launch_bounds__(512, 4) void mega_kernel(
    const float* __restrict__ sh,
    const float* __restrict__ rank_emb,
    const float* __restrict__ rm_w1, const float* __restrict__ rm_b1,
    const float* __restrict__ rm_w2, const float* __restrict__ rm_b2,
    const float* __restrict__ mx_w1, const float* __restrict__ mx_b1,
    const float* __restrict__ mx_w2, const float* __restrict__ mx_b2,
    const float* __restrict__ my_w1, const float* __restrict__ my_b1,
    const float* __restrict__ my_w2, const float* __restrict__ my_b2,
    const float* __restrict__ ax_w1, const float* __restrict__ ax_b1,
    const float* __restrict__ ax_w2, const float* __restrict__ ax_b2,
    const float* __restrict__ ay_w1, const float* __restrict__ ay_b1,
    const float* __restrict__ ay_w2, const float* __restrict__ ay_b2,
    float* __restrict__ Pcat)
{
    __shared__ __align__(16) float sh_s[4][256];     // 4 KB
    __shared__ __align__(16) float hdn_s[4][256];    // 4 KB
    __shared__ __align__(16) float rf_s[4][256];     // 4 KB
    __shared__ __align__(16) float hc_s[2][4][256];  // 8 KB
    __shared__ __align__(16) float re_ps[2][256];    // 2 KB
    __shared__ __align__(16) float remb_s[256];      // 1 KB   (total ~23 KB)
    const int tid = threadIdx.x;
    const int blk = blockIdx.x;
    const int r = blk % 24;          // blk % 8 == r % 8: rank stays on one XCD
    const int bt = blk / 24;         // 0..15
    const int b0 = bt * 4;
    const int col = tid & 255, rh = tid >> 8;
    const int r0 = rh * 2;

    // stage: 4 sh rows (256 float4) + rank_emb row (64 float4)
    if (tid < 256) {
        ((float4*)sh_s)[tid] = ((const float4*)sh)[(size_t)b0 * 64 + tid];
    } else if (tid < 320) {
        int j4 = tid - 256;
        ((float4*)remb_s)[j4] = ((const float4*)rank_emb)[(size_t)r * 64 + j4];
    }
    __syncthreads();

    // prebias split across halves: re_ps[rh] = rank_emb @ rm_w1[r, 256+rh*128 : +128, :]
    {
        float accp = 0.f;
        const float* wb = rm_w1 + ((size_t)r * 512 + 256 + rh * 128) * 256 + col;
        const int o = rh * 128;
        #pragma unroll 4
        for (int d = 0; d < 128; d += 4) {
            float w0 = wb[(size_t)(d + 0) * 256], w1 = wb[(size_t)(d + 1) * 256];
            float w2 = wb[(size_t)(d + 2) * 256], w3 = wb[(size_t)(d + 3) * 256];
            float4 e = *(const float4*)&remb_s[o + d];
            accp += e.x * w0 + e.y * w1 + e.z * w2 + e.w * w3;
        }
        re_ps[rh][col] = accp;
    }
    __syncthreads();

    // L3: hdn = leaky(sh @ rm_w1[r, :256, :] + rm_b1 + prebias), 2 rows per thread
    {
        float bv = rm_b1[r * 256 + col] + re_ps[0][col] + re_ps[1][col];
        float a0 = bv, a1 = bv;
        const float* wp = rm_w1 + (size_t)r * 512 * 256 + col;
        #pragma unroll 4
        for (int d = 0; d < 256; d += 4) {
            float w0 = wp[(size_t)(d + 0) * 256], w1 = wp[(size_t)(d + 1) * 256];
            float w2 = wp[(size_t)(d + 2) * 256], w3 = wp[(size_t)(d + 3) * 256];
            float4 s0 = *(const float4*)&sh_s[r0 + 0][d];
            float4 s1 = *(const float4*)&sh_s[r0 + 1][d];
            a0 += s0.x * w0 + s0.y * w1 + s0.z * w2 + s0.w * w3;
            a1 += s1.x * w0 + s1.y * w1 + s1.z * w2 + s1.w * w3;
        }
        hdn_s[r0 + 0][col] = leaky(a0); hdn_s[r0 + 1][col] = leaky(a1);
    }
    __syncthreads();

    // L4: rf = hdn @ rm_w2[r] + rm_b2[r] (no activation), 2 rows per thread
    {
        float bv = rm_b2[r * 256 + col];
        float a0 = bv, a1 = bv;
        const float* wp = rm_w2 + (size_t)r * 65536 + col;
        #pragma unroll 4
        for (int d = 0; d < 256; d += 4) {
            float w0 = wp[(size_t)(d + 0) * 256], w1 = wp[(size_t)(d + 1) * 256];
            float w2 = wp[(size_t)(d + 2) * 256], w3 = wp[(size_t)(d + 3) * 256];
            float4 s0 = *(const float4*)&hdn_s[r0 + 0][d];
            float4 s1 = *(const float4*)&hdn_s[r0 + 1][d];
            a0 += s0.x * w0 + s0.y * w1 + s0.z * w2 + s0.w * w3;
            a1 += s1.x * w0 + s1.y * w1 + s1.z * w2 + s1.w * w3;
        }
        rf_s[r0 + 0][col] = a0; rf_s[r0 + 1][col] = a1;
    }
    __syncthreads();

    // head selection: head = rh.  r<16: head0=mx(y=r), head1=my(y=16+r);
    // r>=16: rw=r-16: head0=ax(y=32+rw), head1=ay(y=40+rw)
    const float *W1, *B1, *W2, *B2; int y;
    if (r < 16) {
        if (rh == 0) { y = r;      W1 = mx_w1 + (size_t)r * 65536;  B1 = mx_b1 + r * 256;  W2 = mx_w2 + (size_t)r * 6144;  B2 = mx_b2 + r * 24; }
        else         { y = 16 + r; W1 = my_w1 + (size_t)r * 65536;  B1 = my_b1 + r * 256;  W2 = my_w2 + (size_t)r * 6144;  B2 = my_b2 + r * 24; }
    } else {
        int rw = r - 16;
        if (rh == 0) { y = 32 + rw; W1 = ax_w1 + (size_t)rw * 65536; B1 = ax_b1 + rw * 256; W2 = ax_w2 + (size_t)rw * 6144; B2 = ax_b2 + rw * 24; }
        else         { y = 40 + rw; W1 = ay_w1 + (size_t)rw * 65536; B1 = ay_b1 + rw * 256; W2 = ay_w2 + (size_t)rw * 6144; B2 = ay_b2 + rw * 24; }
    }

    // G2 (head rh): hc[rh] = leaky(rf @ W1 + B1), all 4 rows per thread
    {
        float bv = B1[col];
        float acc[4];
        #pragma unroll
        for (int i = 0; i < 4; ++i) acc[i] = bv;
        const float* wp = W1 + col;
        #pragma unroll 4
        for (int d = 0; d < 256; d += 4) {
            float w0 = wp[(size_t)(d + 0) * 256], w1 = wp[(size_t)(d + 1) * 256];
            float w2 = wp[(size_t)(d + 2) * 256], w3 = wp[(size_t)(d + 3) * 256];
            #pragma unroll
            for (int i = 0; i < 4; ++i) {
                float4 s = *(const float4*)&rf_s[i][d];
                acc[i] += s.x * w0 + s.y * w1 + s.z * w2 + s.w * w3;
            }
        }
        #pragma unroll
        for (int i = 0; i < 4; ++i) hc_s[rh][i][col] = leaky(acc[i]);
    }
    __syncthreads();

    // G3 (head rh): Pcat rows for y; 4 rows x 24 cols = 96 active threads per half
    if (col < 96) {
        int row = col / 24, cj = col - row * 24;
        float acc = B2[cj];
        const float* wp = W2 + cj;
        #pragma unroll 4
        for (int d = 0; d < 256; d += 4) {
            float w0 = wp[(size_t)(d + 0) * 24], w1 = wp[(size_t)(d + 1) * 24];
            float w2 = wp[(size_t)(d + 2) * 24], w3 = wp[(size_t)(d + 3) * 24];
            float4 s = *(const float4*)&hc_s[rh][row][d];
            acc += s.x * w0 + s.y * w1 + s.z * w2 + s.w * w3;
        }
        Pcat[(size_t)(b0 + row) * 1152 + y * 24 + cj] = acc;
    }
}

// ---------- D2: fused spline + depth (unchanged).
// Pcat rows: [Px_m 0..15, Py_m 16..31, Px_a 32..39, Py_a 40..47]
__global__ __launch_bounds__(256, 2) void depth_fused_kernel(
    const float* __restrict__ Pcat,
    const float* __restrict__ mult_w, const float* __restrict__ addx_w,
    const float* __restrict__ addy_w, const float* __restrict__ gbias,
    float* __restrict__ out)
{
    __shared__ float cp[48][25];
    __shared__ float sw[33];
    __shared__ __align__(16) float u_s[16][132];
    __shared__ __align__(16) float v_s[16][132];
    __shared__ float dx_s[128], dy_s[128];
    const int tid = threadIdx.x;
    const int b = blockIdx.z, h0 = blockIdx.y * 128, w0 = blockIdx.x * 128;
    for (int idx = tid; idx < 1152; idx += 256)
        cp[idx / 24][idx % 24] = Pcat[(size_t)b * 1152 + idx];
    if (tid == 0) {
        float e[16], m, s;
        m = -1e30f; for (int i = 0; i < 16; ++i) m = fmaxf(m, mult_w[i]);
        s = 0.f;    for (int i = 0; i < 16; ++i) { e[i] = __expf(mult_w[i] - m); s += e[i]; }
        for (int i = 0; i < 16; ++i) sw[i] = e[i] / s;
        m = -1e30f; for (int i = 0; i < 8; ++i) m = fmaxf(m, addx_w[i]);
        s = 0.f;    for (int i = 0; i < 8; ++i) { e[i] = __expf(addx_w[i] - m); s += e[i]; }
        for (int i = 0; i < 8; ++i) sw[16 + i] = e[i] / s;
        m = -1e30f; for (int i = 0; i < 8; ++i) m = fmaxf(m, addy_w[i]);
        s = 0.f;    for (int i = 0; i < 8; ++i) { e[i] = __expf(addy_w[i] - m); s += e[i]; }
        for (int i = 0; i < 8; ++i) sw[24 + i] = e[i] / s;
        sw[32] = gbias[0];
    }
    __syncthreads();
    {
        const int local = tid & 127;
        const int gpos = (tid < 128 ? w0 : h0) + local;
        const float eps = 0.001f;
        float t = eps + (float)gpos * ((1.f - 2.f * eps) / 511.f);
        float ts = t * 23.f;
        int seg = (int)ts; if (seg > 22) seg = 22;
        float tau = ts - (float)seg;
        tau = fminf(fmaxf(tau, 0.f), 0.9999f);
        float t2 = tau * tau, t3 = t2 * tau;
        float h00 = 2.f * t3 - 3.f * t2 + 1.f;
        float h10 = t3 - 2.f * t2 + tau;
        float h01 = -2.f * t3 + 3.f * t2;
        float h11 = t3 - t2;
        int sm1 = seg > 0 ? seg - 1 : 0;
        int s1 = seg + 1;
        int sp2 = s1 < 23 ? s1 + 1 : 23;
        const float msc = 0.5f / 23.f;
        auto spl = [&](int row) -> float {
            float pk = cp[row][seg], pk1 = cp[row][s1];
            float mk  = msc * (pk1 - cp[row][sm1]);
            float mk1 = msc * (cp[row][sp2] - pk);
            return h00 * pk + h10 * mk + h01 * pk1 + h11 * mk1;
        };
        if (tid < 128) {
            #pragma unroll
            for (int r = 0; r < 16; ++r) u_s[r][local] = sw[r] * spl(r);
            float dx = sw[32];
            #pragma unroll
            for (int r = 0; r < 8; ++r) dx += sw[16 + r] * spl(32 + r);
            dx_s[local] = dx;
        } else {
            #pragma unroll
            for (int r = 0; r < 16; ++r) v_s[r][local] = spl(16 + r);
            float dy = 0.f;
            #pragma unroll
            for (int r = 0; r < 8; ++r) dy += sw[24 + r] * spl(40 + r);
            dy_s[local] = dy;
        }
    }
    __syncthreads();
    const int tw = tid & 15, th = tid >> 4;
    float acc[8][8];
    #pragma unroll
    for (int i = 0; i < 8; ++i)
        #pragma unroll
        for (int j = 0; j < 8; ++j) acc[i][j] = 0.f;
    #pragma unroll
    for (int r = 0; r < 16; ++r) {
        float4 va0 = *(const float4*)&v_s[r][th * 8];
        float4 va1 = *(const float4*)&v_s[r][th * 8 + 4];
        float4 ub0 = *(const float4*)&u_s[r][tw * 8];
        float4 ub1 = *(const float4*)&u_s[r][tw * 8 + 4];
        float va[8] = {va0.x, va0.y, va0.z, va0.w, va1.x, va1.y, va1.z, va1.w};
        float ub[8] = {ub0.x, ub0.y, ub0.z, ub0.w, ub1.x, ub1.y, ub1.z, ub1.w};
        #pragma unroll
        for (int i = 0; i < 8; ++i)
            #pragma unroll
            for (int j = 0; j < 8; ++j)
                acc[i][j] += va[i] * ub[j];
    }
    #pragma unroll
    for (int i = 0; i < 8; ++i) {
        float dyh = dy_s[th * 8 + i];
        float* op = out + (size_t)b * 262144 + (size_t)(h0 + th * 8 + i) * 512 + w0 + tw * 8;
        float4 o0, o1;
        o0.x = acc[i][0] + dx_s[tw * 8 + 0] + dyh;
        o0.y = acc[i][1] + dx_s[tw * 8 + 1] + dyh;
        o0.z = acc[i][2] + dx_s[tw * 8 + 2] + dyh;
        o0.w = acc[i][3] + dx_s[tw * 8 + 3] + dyh;
        o1.x = acc[i][4] + dx_s[tw * 8 + 4] + dyh;
        o1.y = acc[i][5] + dx_s[tw * 8 + 5] + dyh;
        o1.z = acc[i][6] + dx_s[tw * 8 + 6] + dyh;
        o1.w = acc[i][7] + dx_s[tw * 8 + 7] + dyh;
        *(float4*)op = o0;
        *(float4*)(op + 4) = o1;
    }
}

// ---------- host ----------
extern "C" void kernel_launch(void* const* d_in, const int* in_sizes, int n_in,
                              void* d_out, int out_size, void* d_ws, size_t ws_size,
                              hipStream_t stream) {
    const float* in_h     = (const float*)d_in[0];
    const float* rank_emb = (const float*)d_in[1];
    const float* st_w1    = (const float*)d_in[2];
    const float* st_b1    = (const float*)d_in[3];
    const float* st_w2    = (const float*)d_in[4];
    const float* st_b2    = (const float*)d_in[5];
    const float* rm_w1    = (const float*)d_in[6];
    const float* rm_b1    = (const float*)d_in[7];
    const float* rm_w2    = (const float*)d_in[8];
    const float* rm_b2    = (const float*)d_in[9];
    const float* mx_w1    = (const float*)d_in[10];
    const float* mx_b1    = (const float*)d_in[11];
    const float* mx_w2    = (const float*)d_in[12];
    const float* mx_b2    = (const float*)d_in[13];
    const float* my_w1    = (const float*)d_in[14];
    const float* my_b1    = (const float*)d_in[15];
    const float* my_w2    = (const float*)d_in[16];
    const float* my_b2    = (const float*)d_in[17];
    const float* ax_w1    = (const float*)d_in[18];
    const float* ax_b1    = (const float*)d_in[19];
    const float* ax_w2    = (const float*)d_in[20];
    const float* ax_b2    = (const float*)d_in[21];
    const float* ay_w1    = (const float*)d_in[22];
    const float* ay_b1    = (const float*)d_in[23];
    const float* ay_w2    = (const float*)d_in[24];
    const float* ay_b2    = (const float*)d_in[25];
    const float* mult_w   = (const float*)d_in[26];
    const float* addx_w   = (const float*)d_in[27];
    const float* addy_w   = (const float*)d_in[28];
    const float* gbias    = (const float*)d_in[29];
    (void)in_sizes; (void)n_in; (void)out_size; (void)ws_size;

    float* ws = (float*)d_ws;
    float* hid1p = ws;               // 6 x (64x512) = 196608 floats
    float* Pcat  = ws + 196608;      // 64x48x24     = 73728 floats
    float* shbuf = ws + 270336;      // 64x256       = 16384 floats

    // D0: L1 split-K6 -> hid1p[6]
    l1_kernel<<<dim3(32, 1, 6), 256, 0, stream>>>(in_h, st_w1, st_b1, hid1p);

    // D0b: shared layer 2 (once, not per-rank)
    l2_kernel<<<32, 512, 0, stream>>>(hid1p, st_w2, st_b2, shbuf);

    // D1: mega-middle -> Pcat (1D grid, XCD-clustered by rank)
    mega_kernel<<<384, 512, 0, stream>>>(
        shbuf, rank_emb,
        rm_w1, rm_b1, rm_w2, rm_b2,
        mx_w1, mx_b1, mx_w2, mx_b2,
        my_w1, my_b1, my_w2, my_b2,
        ax_w1, ax_b1, ax_w2, ax_b2,
        ay_w1, ay_b1, ay_w2, ay_b2,
        Pcat);

    // D2: fused spline + depth
    depth_fused_kernel<<<dim3(4, 4, 64), 256, 0, stream>>>(
        Pcat, mult_w, addx_w, addy_w, gbias, (float*)d_out);
}